// Round 5
// baseline (141.172 us; speedup 1.0000x reference)
//
#include <hip/hip_runtime.h>
#include <hip/hip_bf16.h>
#include <math.h>

#define B 8
#define LD 128
#define LP 1000
#define LP_PAD 1024              // pad y to 256 float4 quads
#define DIM 128
#define LN_EPS 1e-5f

#define TILES_D (B * LD / 16)    // 64 drug 16-row tiles (exact)
#define TILES_P (B * LP / 16)    // 500 protein 16-row tiles (exact concat)
#define GTILES_D 64              // gated drug tiles
#define GTILES_PB 63             // gated protein tiles PER BATCH (63*16 >= 1000)
#define GTILES_P (8 * GTILES_PB) // 504
#define SEG_D 8
#define SEG_P GTILES_PB

typedef __attribute__((ext_vector_type(8))) short bf16x8;
typedef __attribute__((ext_vector_type(4))) float f32x4;

// fp32 -> bf16 (RNE) via HIP intrinsics; compiler packs pairs into
// v_cvt_pk_bf16_f32 (m240: scalar-cast path beats hand-written asm).
__device__ inline short f2bf(float f) {
    return __bfloat16_as_short(__float2bfloat16(f));
}

__device__ inline bf16x8 cvt8(float4 lo, float4 hi) {
    bf16x8 r;
    r[0] = f2bf(lo.x); r[1] = f2bf(lo.y); r[2] = f2bf(lo.z); r[3] = f2bf(lo.w);
    r[4] = f2bf(hi.x); r[5] = f2bf(hi.y); r[6] = f2bf(hi.z); r[7] = f2bf(hi.w);
    return r;
}

// ---------------------------------------------------------------------------
// Kernel 1: MFMA GEMV  out = X @ W^T + b.  One wave = one 16-row tile.
// W read as fp32, converted to bf16 in-register (no separate conv kernel).
// ---------------------------------------------------------------------------
__global__ __launch_bounds__(256) void mfma_gemv(
        const float* __restrict__ Xd, const float* __restrict__ Xp,
        const float* __restrict__ Wd, const float* __restrict__ bd,
        const float* __restrict__ Wp, const float* __restrict__ bp,
        float* __restrict__ outd, float* __restrict__ outp) {
    const int wave = (blockIdx.x * 256 + threadIdx.x) >> 6;
    const int lane = threadIdx.x & 63;

    const float* X; const float* W; const float* bias; float* out; int m0;
    if (wave < TILES_D) { X = Xd; W = Wd; bias = bd; out = outd; m0 = wave * 16; }
    else { X = Xp; W = Wp; bias = bp; out = outp; m0 = (wave - TILES_D) * 16; }

    const int arow = lane & 15;          // A row in tile / W row selector
    const int kgrp = lane >> 4;          // k-group: k offset kgrp*8

    bf16x8 afrag[4];
    {
        const float* xrow = X + (size_t)(m0 + arow) * DIM + kgrp * 8;
#pragma unroll
        for (int kk = 0; kk < 4; ++kk)
            afrag[kk] = cvt8(*(const float4*)(xrow + kk * 32),
                             *(const float4*)(xrow + kk * 32 + 4));
    }

    const int ocol = lane & 15;
    const int orow = (lane >> 4) * 4;
#pragma unroll
    for (int nt = 0; nt < 8; ++nt) {
        const float* wrow = W + (size_t)(nt * 16 + arow) * DIM + kgrp * 8;
        f32x4 c = {0.f, 0.f, 0.f, 0.f};
#pragma unroll
        for (int kk = 0; kk < 4; ++kk) {
            const bf16x8 bfrag = cvt8(*(const float4*)(wrow + kk * 32),
                                      *(const float4*)(wrow + kk * 32 + 4));
            c = __builtin_amdgcn_mfma_f32_16x16x32_bf16(afrag[kk], bfrag, c, 0, 0, 0);
        }
        const float bv = bias[nt * 16 + ocol];
#pragma unroll
        for (int r = 0; r < 4; ++r)
            out[(size_t)(m0 + orow + r) * DIM + nt * 16 + ocol] = c[r] + bv;
    }
}

// ---------------------------------------------------------------------------
// Kernel 2: per (b,d): row/col mean of relu(x_i + y_j).
// Col pass: both y-pairs per thread share one i-loop (1 xs read / 4 cells).
// Row pass: float4 (b128) y reads, 8-lane broadcast, conflict-free.
// ---------------------------------------------------------------------------
__global__ __launch_bounds__(256) void pairwise(
        const float* __restrict__ d_att, const float* __restrict__ p_att,
        float* __restrict__ Mc, float* __restrict__ Mp) {
    const int blk = blockIdx.x;
    const int b = blk >> 7;
    const int d = blk & (DIM - 1);
    const int t = threadIdx.x;

    __shared__ float xs[LD];
    __shared__ float ys[LP_PAD];
    __shared__ float red[LD * 8];

    if (t < LD) xs[t] = d_att[(b * LD + t) * DIM + d];
    for (int j = t; j < LP_PAD; j += 256) {
        ys[j] = (j < LP) ? p_att[(b * LP + j) * DIM + d] : -1e30f;
    }
    __syncthreads();

    const float2* ys2 = (const float2*)ys;
    const float4* ys4 = (const float4*)ys;

    // ---- column sums -> Mp: pairs p0 = t, p1 = t + 256, single i-loop
    {
        const float2 y0 = ys2[t];
        const float2 y1 = ys2[t + 256];
        float2 acc0 = make_float2(0.f, 0.f), acc1 = acc0;
#pragma unroll 8
        for (int i = 0; i < LD; ++i) {
            const float x = xs[i];
            acc0.x += fmaxf(0.f, x + y0.x);
            acc0.y += fmaxf(0.f, x + y0.y);
            acc1.x += fmaxf(0.f, x + y1.x);
            acc1.y += fmaxf(0.f, x + y1.y);
        }
        const int j0 = 2 * t;
        Mp[(b * LP + j0) * DIM + d]     = acc0.x * (1.f / (float)LD);
        Mp[(b * LP + j0 + 1) * DIM + d] = acc0.y * (1.f / (float)LD);
        const int j1 = 512 + 2 * t;
        if (j1 < LP)     Mp[(b * LP + j1) * DIM + d]     = acc1.x * (1.f / (float)LD);
        if (j1 + 1 < LP) Mp[(b * LP + j1 + 1) * DIM + d] = acc1.y * (1.f / (float)LD);
    }

    // ---- row sums -> Mc (thread = 4 rows x 1/8 of y; 32 b128 reads)
    {
        const int rq = t >> 3;           // row quad 0..31
        const int sl = t & 7;            // y slice 0..7
        const float x0 = xs[4 * rq + 0];
        const float x1 = xs[4 * rq + 1];
        const float x2 = xs[4 * rq + 2];
        const float x3 = xs[4 * rq + 3];
        float2 a0 = make_float2(0.f, 0.f), a1 = a0, a2 = a0, a3 = a0;
        for (int q = sl; q < LP_PAD / 4; q += 8) {
            const float4 y = ys4[q];
            a0.x += fmaxf(0.f, x0 + y.x); a0.y += fmaxf(0.f, x0 + y.y);
            a0.x += fmaxf(0.f, x0 + y.z); a0.y += fmaxf(0.f, x0 + y.w);
            a1.x += fmaxf(0.f, x1 + y.x); a1.y += fmaxf(0.f, x1 + y.y);
            a1.x += fmaxf(0.f, x1 + y.z); a1.y += fmaxf(0.f, x1 + y.w);
            a2.x += fmaxf(0.f, x2 + y.x); a2.y += fmaxf(0.f, x2 + y.y);
            a2.x += fmaxf(0.f, x2 + y.z); a2.y += fmaxf(0.f, x2 + y.w);
            a3.x += fmaxf(0.f, x3 + y.x); a3.y += fmaxf(0.f, x3 + y.y);
            a3.x += fmaxf(0.f, x3 + y.z); a3.y += fmaxf(0.f, x3 + y.w);
        }
        red[(4 * rq + 0) * 8 + sl] = a0.x + a0.y;
        red[(4 * rq + 1) * 8 + sl] = a1.x + a1.y;
        red[(4 * rq + 2) * 8 + sl] = a2.x + a2.y;
        red[(4 * rq + 3) * 8 + sl] = a3.x + a3.y;
    }
    __syncthreads();
    if (t < LD) {
        float s = 0.f;
#pragma unroll
        for (int k = 0; k < 8; ++k) s += red[t * 8 + k];
        Mc[(b * LD + t) * DIM + d] = s * (1.f / (float)LP);
    }
}

// ---------------------------------------------------------------------------
// Kernel 3: MFMA gated GEMV + fused sigmoid gate * conv + per-tile col max.
// ---------------------------------------------------------------------------
__global__ __launch_bounds__(256) void mfma_gated(
        const float* __restrict__ Mc, const float* __restrict__ Mp,
        const float* __restrict__ W, const float* __restrict__ bias,
        const float* __restrict__ convd, const float* __restrict__ convp,
        float* __restrict__ pd, float* __restrict__ pp) {
    const int wave = (blockIdx.x * 256 + threadIdx.x) >> 6;
    const int lane = threadIdx.x & 63;

    const float* M; const float* conv; float* part; int m0; int valid;
    if (wave < GTILES_D) {
        M = Mc; conv = convd; part = pd + wave * DIM; m0 = wave * 16; valid = 16;
    } else {
        const int pb = wave - GTILES_D;
        const int b = pb / GTILES_PB;
        const int s = pb - b * GTILES_PB;
        M = Mp; conv = convp; part = pp + pb * DIM;
        m0 = b * LP + s * 16;
        valid = (s * 16 + 16 <= LP) ? 16 : (LP - s * 16);
    }

    const int arow = lane & 15;
    const int kgrp = lane >> 4;

    bf16x8 afrag[4];
    if (arow < valid) {
        const float* mrow = M + (size_t)(m0 + arow) * DIM + kgrp * 8;
#pragma unroll
        for (int kk = 0; kk < 4; ++kk)
            afrag[kk] = cvt8(*(const float4*)(mrow + kk * 32),
                             *(const float4*)(mrow + kk * 32 + 4));
    } else {
        bf16x8 z;
#pragma unroll
        for (int j = 0; j < 8; ++j) z[j] = 0;
#pragma unroll
        for (int kk = 0; kk < 4; ++kk) afrag[kk] = z;
    }

    const int ocol = lane & 15;
    const int orow = (lane >> 4) * 4;
#pragma unroll
    for (int nt = 0; nt < 8; ++nt) {
        const float* wrow = W + (size_t)(nt * 16 + arow) * DIM + kgrp * 8;
        f32x4 c = {0.f, 0.f, 0.f, 0.f};
#pragma unroll
        for (int kk = 0; kk < 4; ++kk) {
            const bf16x8 bfrag = cvt8(*(const float4*)(wrow + kk * 32),
                                      *(const float4*)(wrow + kk * 32 + 4));
            c = __builtin_amdgcn_mfma_f32_16x16x32_bf16(afrag[kk], bfrag, c, 0, 0, 0);
        }
        const float bv = bias[nt * 16 + ocol];
        float m = -INFINITY;
#pragma unroll
        for (int r = 0; r < 4; ++r) {
            const int rr = orow + r;
            if (rr < valid) {
                const float att = 1.f / (1.f + __expf(-(c[r] + bv)));
                const float v = conv[(size_t)(m0 + rr) * DIM + nt * 16 + ocol] * (0.5f + att);
                m = fmaxf(m, v);
            }
        }
        m = fmaxf(m, __shfl_xor(m, 16));
        m = fmaxf(m, __shfl_xor(m, 32));
        if (lane < 16) part[nt * 16 + lane] = m;
    }
}

// ---------------------------------------------------------------------------
// Kernel 4: reduce partials + LayerNorm.
// ---------------------------------------------------------------------------
__global__ __launch_bounds__(256) void maxln_final(
        const float* __restrict__ pd, const float* __restrict__ pp,
        const float* __restrict__ gamma1, const float* __restrict__ beta1,
        const float* __restrict__ gamma2, const float* __restrict__ beta2,
        float* __restrict__ out) {
    const int blk = blockIdx.x;
    const int kind = blk >> 3;
    const int b = blk & 7;
    const int t = threadIdx.x & (DIM - 1);
    const int h = threadIdx.x >> 7;

    float m = -INFINITY;
    if (kind == 0) {
        const float* base = pd + b * SEG_D * DIM;
        for (int s = h; s < SEG_D; s += 2) m = fmaxf(m, base[s * DIM + t]);
    } else {
        const float* base = pp + b * SEG_P * DIM;
        for (int s = h; s < SEG_P; s += 2) m = fmaxf(m, base[s * DIM + t]);
    }

    __shared__ float sm[2][DIM];
    sm[h][t] = m;
    __syncthreads();

    __shared__ float s1[DIM];
    __shared__ float s2[DIM];
    if (threadIdx.x < DIM) {
        m = fmaxf(sm[0][t], sm[1][t]);
        sm[0][t] = m;
        s1[t] = m;
        s2[t] = m * m;
    }
    __syncthreads();
    for (int off = DIM / 2; off > 0; off >>= 1) {
        if (threadIdx.x < off) {
            s1[threadIdx.x] += s1[threadIdx.x + off];
            s2[threadIdx.x] += s2[threadIdx.x + off];
        }
        __syncthreads();
    }
    if (threadIdx.x < DIM) {
        const float mu = s1[0] * (1.f / (float)DIM);
        const float var = s2[0] * (1.f / (float)DIM) - mu * mu;
        const float inv = rsqrtf(var + LN_EPS);
        const float* gamma = kind ? gamma2 : gamma1;
        const float* beta  = kind ? beta2  : beta1;
        out[blk * DIM + t] = (sm[0][t] - mu) * inv * gamma[t] + beta[t];
    }
}

// ---------------------------------------------------------------------------
extern "C" void kernel_launch(void* const* d_in, const int* in_sizes, int n_in,
                              void* d_out, int out_size, void* d_ws, size_t ws_size,
                              hipStream_t stream) {
    const float* drug_conv    = (const float*)d_in[0];
    const float* protein_conv = (const float*)d_in[1];
    const float* W_d   = (const float*)d_in[2];
    const float* b_d   = (const float*)d_in[3];
    const float* W_p   = (const float*)d_in[4];
    const float* b_p   = (const float*)d_in[5];
    const float* W_att = (const float*)d_in[6];
    const float* b_att = (const float*)d_in[7];
    const float* gamma1 = (const float*)d_in[8];
    const float* beta1  = (const float*)d_in[9];
    const float* gamma2 = (const float*)d_in[10];
    const float* beta2  = (const float*)d_in[11];
    float* out = (float*)d_out;

    // workspace layout (floats)
    float* ws = (float*)d_ws;
    const size_t n_datt = (size_t)B * LD * DIM;            // 131072
    const size_t n_patt = (size_t)B * LP * DIM;            // 1024000
    float* d_att = ws;
    float* p_att = ws + n_datt;
    float* Mc    = ws + n_datt + n_patt;
    float* Mp    = ws + n_datt + n_patt + n_datt;
    // partials alias the dead d_att/p_att region
    float* pd = ws;                                        // 64*128
    float* pp = ws + GTILES_D * DIM;                       // 504*128

    mfma_gemv<<<(TILES_D + TILES_P) / 4, 256, 0, stream>>>(
        drug_conv, protein_conv, W_d, b_d, W_p, b_p, d_att, p_att);
    pairwise<<<B * DIM, 256, 0, stream>>>(d_att, p_att, Mc, Mp);
    mfma_gated<<<(GTILES_D + GTILES_P) / 4, 256, 0, stream>>>(
        Mc, Mp, W_att, b_att, drug_conv, protein_conv, pd, pp);
    maxln_final<<<16, 256, 0, stream>>>(pd, pp, gamma1, beta1, gamma2, beta2, out);
}